// Round 8
// baseline (191.422 us; speedup 1.0000x reference)
//
#include <hip/hip_runtime.h>
#include <stdint.h>

// ---------------------------------------------------------------------------
// MultiheadMaskedAttention (B=2, S=2048, H=1024, 16 heads x d=64)
// R8: attn critical-path fix. (1) complementary q-tile pairing: block p owns
// 64-row q-tiles {p, 31-p} (waves 0-1 / 2-3) -> every block stages 32-p
// tiles, uniform aggregate work, balanced finish times. (2) KV double-buffer:
// prefetch t+1 issued right after the top barrier (other buffer), one
// barrier/iter; the pre-barrier vmcnt drain overlaps a full compute iter.
// GEMMs/prep unchanged from R7.
// ---------------------------------------------------------------------------

typedef __bf16 bf16;
typedef __attribute__((ext_vector_type(8))) __bf16 bf16x8;
typedef __attribute__((ext_vector_type(4))) __bf16 bf16x4;
typedef __attribute__((ext_vector_type(4))) float floatx4;

#define SCL 0.18033688011112042f  // (1/sqrt(64)) * log2(e)

__device__ __forceinline__ floatx4 mfma_bf16(bf16x8 a, bf16x8 b, floatx4 c) {
  // A: m=lane&15, k=quad*8+j ; B: n=lane&15, k=quad*8+j ; D: n=lane&15,
  // m=quad*4+reg  [verified m89/m91]
  return __builtin_amdgcn_mfma_f32_16x16x32_bf16(a, b, c, 0, 0, 0);
}

__device__ __forceinline__ void cp_g2l_16(const bf16* g, bf16* l) {
  // async global->LDS, 16B/lane; LDS dest = wave-uniform base + lane*16
  __builtin_amdgcn_global_load_lds(
      (const __attribute__((address_space(1))) void*)g,
      (__attribute__((address_space(3))) void*)l, 16, 0, 0);
}

// ---- merged prep: cast x -> bf16 ; cast+transpose w_qkv, w_o ----
__global__ __launch_bounds__(256) void prep_kernel(
    const float* __restrict__ x, bf16* __restrict__ xb,
    const float* __restrict__ w_qkv, bf16* __restrict__ wqkvt,
    const float* __restrict__ w_o, bf16* __restrict__ wot) {
  const int b = blockIdx.x;
  const int tid = threadIdx.x;
  if (b < 4096) {
    const int i = (b * 256 + tid) * 4;
    floatx4 v = *(const floatx4*)(x + i);
    bf16x4 o;
    o[0] = (bf16)v[0]; o[1] = (bf16)v[1]; o[2] = (bf16)v[2]; o[3] = (bf16)v[3];
    *(bf16x4*)(xb + i) = o;
    return;
  }
  __shared__ float tile[32][33];
  const float* W; bf16* Wt; int K, N, n0, k0;
  if (b < 7168) {
    const int bb = b - 4096;
    W = w_qkv; Wt = wqkvt; K = 1024; N = 3072;
    n0 = (bb % 96) * 32; k0 = (bb / 96) * 32;
  } else {
    const int bb = b - 7168;
    W = w_o; Wt = wot; K = 1024; N = 1024;
    n0 = (bb & 31) * 32; k0 = (bb >> 5) * 32;
  }
  const int tx = tid & 31, ty = tid >> 5;
  for (int i = 0; i < 4; ++i)
    tile[ty + 8 * i][tx] = W[(size_t)(k0 + ty + 8 * i) * N + n0 + tx];
  __syncthreads();
  for (int i = 0; i < 4; ++i)
    Wt[(size_t)(n0 + ty + 8 * i) * K + k0 + tx] = (bf16)tile[tx][ty + 8 * i];
}

// ---- GEMM: C = A(M x K bf16 rm) * Bt(N x K bf16 rm)^T + bias ----
template <int MODE, int MI>
__global__ __launch_bounds__(256, 3) void gemm_bt_kernel(
    const bf16* __restrict__ A, const bf16* __restrict__ Bt,
    const float* __restrict__ bias, float* __restrict__ outF,
    bf16* __restrict__ qb, bf16* __restrict__ kb, bf16* __restrict__ vtb,
    int N, int K) {
  constexpr int BM = MI * 32;
  __shared__ bf16 As[BM * 32];
  __shared__ bf16 Bs[128 * 32];
  const int tid = threadIdx.x;
  const int w = tid >> 6, lane = tid & 63;
  const int l16 = lane & 15, quad = lane >> 4;
  const int m0 = blockIdx.y * BM, n0 = blockIdx.x * 128;
  const int wm = (w & 1) * (BM / 2), wn = (w >> 1) * 64;

  const int arow = w * (BM / 4) + (lane >> 2);
  const int acol = (lane & 3) * 8;
  const bf16* Ag = A + (size_t)(m0 + arow) * K + acol;
  bf16* Al = As + arow * 32 + acol;
  const int brow = w * 32 + (lane >> 2);
  const bf16* Bg = Bt + (size_t)(n0 + brow) * K + acol;
  bf16* Bl = Bs + brow * 32 + acol;

  floatx4 acc[MI][4];
#pragma unroll
  for (int i = 0; i < MI; ++i)
#pragma unroll
    for (int j = 0; j < 4; ++j) acc[i][j] = (floatx4){0.f, 0.f, 0.f, 0.f};

  for (int k0 = 0; k0 < K; k0 += 32) {
    __syncthreads();
    cp_g2l_16(Ag + k0, Al);
    if (MI == 4) cp_g2l_16(Ag + (size_t)16 * K + k0, Al + 16 * 32);
    cp_g2l_16(Bg + k0, Bl);
    cp_g2l_16(Bg + (size_t)16 * K + k0, Bl + 16 * 32);
    __syncthreads();
    bf16x8 af[MI], bfr[4];
#pragma unroll
    for (int i = 0; i < MI; ++i)
      af[i] = *(const bf16x8*)(&As[(wm + i * 16 + l16) * 32 + quad * 8]);
#pragma unroll
    for (int j = 0; j < 4; ++j)
      bfr[j] = *(const bf16x8*)(&Bs[(wn + j * 16 + l16) * 32 + quad * 8]);
#pragma unroll
    for (int i = 0; i < MI; ++i)
#pragma unroll
      for (int j = 0; j < 4; ++j)
        acc[i][j] = mfma_bf16(af[i], bfr[j], acc[i][j]);
  }

#pragma unroll
  for (int i = 0; i < MI; ++i)
#pragma unroll
    for (int j = 0; j < 4; ++j) {
      const int nn = n0 + wn + j * 16 + l16;
      const float bv = bias[nn];
      const int mbase = m0 + wm + i * 16 + quad * 4;
      if (MODE == 1) {
#pragma unroll
        for (int r = 0; r < 4; ++r)
          outF[(size_t)(mbase + r) * N + nn] = acc[i][j][r] + bv;
      } else {
        const int which = nn >> 10;  // uniform per block
        const int rem = nn & 1023;
        const int h = rem >> 6, d = rem & 63;
        const int b = mbase >> 11, s = mbase & 2047;
        const size_t bh = (size_t)(b * 16 + h);
        if (which == 2) {
          bf16x4 pk;
#pragma unroll
          for (int r = 0; r < 4; ++r) pk[r] = (bf16)(acc[i][j][r] + bv);
          *(bf16x4*)(vtb + (bh * 64 + d) * 2048 + s) = pk;
        } else if (which == 0) {
#pragma unroll
          for (int r = 0; r < 4; ++r)
            qb[(bh * 2048 + s + r) * 64 + d] = (bf16)((acc[i][j][r] + bv) * SCL);
        } else {
#pragma unroll
          for (int r = 0; r < 4; ++r)
            kb[(bh * 2048 + s + r) * 64 + d] = (bf16)(acc[i][j][r] + bv);
        }
      }
    }
}

// ---- Flash attention, causal: block-shared dbuf KV staging, paired tiles. -
// 512 blocks: block = (head, pair p). Waves 0-1 own 64-row q-tile p, waves
// 2-3 own q-tile 31-p. Staging loop runs 32-p KV tiles (the max of the two
// ranges); waves past their diagonal skip compute. KV tiles double-buffered:
// prefetch t+1 issued right after the top barrier.
__global__ __launch_bounds__(256, 3) void attn_kernel(
    const bf16* __restrict__ Qb, const bf16* __restrict__ Kb,
    const bf16* __restrict__ Vtb, bf16* __restrict__ attnb) {
  __shared__ bf16 Ks[2][4096];     // [buf][64 s-rows x 64 d] swizzled chunks
  __shared__ bf16 Vs[2][4096];     // [buf][64 d-rows x 64 s] swizzled chunks
  __shared__ bf16 Ps[4 * 2368];    // per-wave padded P (R4 layout)
  const int bid = blockIdx.x;
  const int bh = (bid & 7) * 4 + ((bid >> 3) & 3);  // 4 heads per XCD
  const int p = bid >> 5;                           // pair id 0..15
  const int tid = threadIdx.x;
  const int w = tid >> 6, lane = tid & 63;
  const int l16 = lane & 15, quad = lane >> 4;
  const int qt = (w < 2) ? p : (31 - p);   // this wave's 64-row q-tile
  const int q0 = qt * 64 + (w & 1) * 32;   // this wave's 32 q-rows
  const int b = bh >> 4, h = bh & 15;
  const bf16* Qh = Qb + (size_t)bh * 2048 * 64;
  const bf16* Kh = Kb + (size_t)bh * 2048 * 64;
  const bf16* Vh = Vtb + (size_t)bh * 64 * 2048;
  bf16* Pw = Ps + w * 2368;
  const int pw_wr = quad * 288 + (quad >> 1) * 16 + l16;    // row=quad*4+r
  const int pw_rd = l16 * 72 + (l16 >> 3) * 16 + quad * 8;  // row=l16

  const int nt = 32 - p;     // staging iterations (B-side range, the max)
  const int wdiag = qt;      // this wave's diagonal KV tile

  // staging chunk ids (16B chunks, 512 per tile): this thread copies c0,c1
  const int c0 = tid, c1 = 256 + tid;
  // source element offset for dest chunk c: row=c>>3, slot=c&7 ->
  // src chunk (slot-row)&7  (rotation swizzle; conflict-free b128 readback)
  const int ksrc0 = (c0 >> 3) * 64 + (((c0 & 7) - (c0 >> 3)) & 7) * 8;
  const int ksrc1 = (c1 >> 3) * 64 + (((c1 & 7) - (c1 >> 3)) & 7) * 8;
  const int vsrc0 = (c0 >> 3) * 2048 + (((c0 & 7) - (c0 >> 3)) & 7) * 8;
  const int vsrc1 = (c1 >> 3) * 2048 + (((c1 & 7) - (c1 >> 3)) & 7) * 8;

  // Q frags held in registers all kernel
  bf16x8 qf[2][2];
#pragma unroll
  for (int mb = 0; mb < 2; ++mb)
#pragma unroll
    for (int kq = 0; kq < 2; ++kq)
      qf[mb][kq] = *(const bf16x8*)(Qh + (size_t)(q0 + mb * 16 + l16) * 64 +
                                    kq * 32 + quad * 8);
  bf16x8 ones;
#pragma unroll
  for (int j = 0; j < 8; ++j) ones[j] = (bf16)1.0f;

  floatx4 O[2][4], Ol[2];
#pragma unroll
  for (int mb = 0; mb < 2; ++mb) {
#pragma unroll
    for (int nd = 0; nd < 4; ++nd) O[mb][nd] = (floatx4){0.f, 0.f, 0.f, 0.f};
    Ol[mb] = (floatx4){0.f, 0.f, 0.f, 0.f};
  }

  // prologue: stage tile 0 into buffer 0
  cp_g2l_16(Kh + ksrc0, &Ks[0][c0 * 8]);
  cp_g2l_16(Kh + ksrc1, &Ks[0][c1 * 8]);
  cp_g2l_16(Vh + vsrc0, &Vs[0][c0 * 8]);
  cp_g2l_16(Vh + vsrc1, &Vs[0][c1 * 8]);

  int cur = 0;
  for (int t = 0; t < nt; ++t, cur ^= 1) {
    __syncthreads();  // buf[cur] staged (vmcnt drained pre-barrier), and all
                      // waves done reading buf[cur^1] from iter t-1
    // prefetch t+1 into the other buffer (overlaps this whole iteration)
    if (t + 1 < nt) {
      const bf16* KtG = Kh + (size_t)(t + 1) * 4096;
      const bf16* VtG = Vh + (t + 1) * 64;
      const int nb = cur ^ 1;
      cp_g2l_16(KtG + ksrc0, &Ks[nb][c0 * 8]);
      cp_g2l_16(KtG + ksrc1, &Ks[nb][c1 * 8]);
      cp_g2l_16(VtG + vsrc0, &Vs[nb][c0 * 8]);
      cp_g2l_16(VtG + vsrc1, &Vs[nb][c1 * 8]);
    }

    if (t > wdiag) continue;  // fully-masked tile for this wave (barrier is
                              // next loop iteration's top — all waves reach it)
    const bool diag = (t == wdiag);
    const bf16* KsC = Ks[cur];
    const bf16* VsC = Vs[cur];

    // K frags from LDS (swizzled addrs)
    bf16x8 kf[4][2];
#pragma unroll
    for (int nk = 0; nk < 4; ++nk)
#pragma unroll
      for (int kq = 0; kq < 2; ++kq) {
        const int row = nk * 16 + l16;
        kf[nk][kq] = *(const bf16x8*)(
            &KsC[row * 64 + ((kq * 4 + quad + row) & 7) * 8]);
      }

    // ---- mb0: QK -> mask -> exp -> P write ----
    {
      floatx4 sf[4];
#pragma unroll
      for (int nk = 0; nk < 4; ++nk) {
        floatx4 a = (floatx4){0.f, 0.f, 0.f, 0.f};
        a = mfma_bf16(qf[0][0], kf[nk][0], a);
        a = mfma_bf16(qf[0][1], kf[nk][1], a);
        sf[nk] = a;
      }
#pragma unroll
      for (int nk = 0; nk < 4; ++nk)
#pragma unroll
        for (int r = 0; r < 4; ++r) {
          float s = sf[nk][r];
          if (diag) {
            const int kc = t * 64 + nk * 16 + l16;
            const int qrow = q0 + quad * 4 + r;
            s = (kc <= qrow) ? s : -1e30f;
          }
          Pw[pw_wr + r * 72 + nk * 16] = (bf16)__builtin_amdgcn_exp2f(s);
        }
    }
    // ---- mb1: QK (last use of kf) -> mask -> exp -> P write ----
    floatx4 sg[4];
#pragma unroll
    for (int nk = 0; nk < 4; ++nk) {
      floatx4 a = (floatx4){0.f, 0.f, 0.f, 0.f};
      a = mfma_bf16(qf[1][0], kf[nk][0], a);
      a = mfma_bf16(qf[1][1], kf[nk][1], a);
      sg[nk] = a;
    }
    // V frags from LDS (kf regs reusable; latency hidden under exp below)
    bf16x8 vf[4][2];
#pragma unroll
    for (int nd = 0; nd < 4; ++nd)
#pragma unroll
      for (int kq = 0; kq < 2; ++kq) {
        const int row = nd * 16 + l16;
        vf[nd][kq] = *(const bf16x8*)(
            &VsC[row * 64 + ((kq * 4 + quad + row) & 7) * 8]);
      }
#pragma unroll
    for (int nk = 0; nk < 4; ++nk)
#pragma unroll
      for (int r = 0; r < 4; ++r) {
        float s = sg[nk][r];
        if (diag) {
          const int kc = t * 64 + nk * 16 + l16;
          const int qrow = q0 + 16 + quad * 4 + r;
          s = (kc <= qrow) ? s : -1e30f;
        }
        Pw[pw_wr + 1184 + r * 72 + nk * 16] = (bf16)__builtin_amdgcn_exp2f(s);
      }

    // ---- P C-layout -> A-layout (per-wave LDS); O += P V; l += P * 1 ----
#pragma unroll
    for (int mb = 0; mb < 2; ++mb) {
      bf16x8 pf[2];
      pf[0] = *(const bf16x8*)(&Pw[pw_rd + mb * 1184]);
      pf[1] = *(const bf16x8*)(&Pw[pw_rd + mb * 1184 + 32]);
#pragma unroll
      for (int nd = 0; nd < 4; ++nd) {
        floatx4 o = O[mb][nd];
        o = mfma_bf16(pf[0], vf[nd][0], o);
        o = mfma_bf16(pf[1], vf[nd][1], o);
        O[mb][nd] = o;
      }
      Ol[mb] = mfma_bf16(pf[0], ones, Ol[mb]);
      Ol[mb] = mfma_bf16(pf[1], ones, Ol[mb]);
    }
  }

  // epilogue: each wave owns its 32 rows outright (no combine)
#pragma unroll
  for (int mb = 0; mb < 2; ++mb)
#pragma unroll
    for (int r = 0; r < 4; ++r) {
      const int qrow = q0 + mb * 16 + quad * 4 + r;
      const float inv = 1.f / Ol[mb][r];
#pragma unroll
      for (int nd = 0; nd < 4; ++nd)
        attnb[((size_t)(b * 2048 + qrow)) * 1024 + h * 64 + nd * 16 + l16] =
            (bf16)(O[mb][nd][r] * inv);
    }
}

// ---------------------------------------------------------------------------
extern "C" void kernel_launch(void* const* d_in, const int* in_sizes, int n_in,
                              void* d_out, int out_size, void* d_ws, size_t ws_size,
                              hipStream_t stream) {
  const float* x     = (const float*)d_in[0];  // (2,2048,1024)
  const float* w_qkv = (const float*)d_in[1];  // (1024,3072)
  const float* b_qkv = (const float*)d_in[2];  // (3072)
  const float* w_o   = (const float*)d_in[3];  // (1024,1024)
  const float* b_o   = (const float*)d_in[4];  // (1024)
  float* out = (float*)d_out;                  // (2,2048,1024) fp32

  char* ws = (char*)d_ws;
  bf16* xb    = (bf16*)ws; ws += (size_t)4096 * 1024 * 2;
  bf16* wqkvt = (bf16*)ws; ws += (size_t)3072 * 1024 * 2;
  bf16* wot   = (bf16*)ws; ws += (size_t)1024 * 1024 * 2;
  bf16* qb    = (bf16*)ws; ws += (size_t)32 * 2048 * 64 * 2;
  bf16* kb    = (bf16*)ws; ws += (size_t)32 * 2048 * 64 * 2;
  bf16* vtb   = (bf16*)ws; ws += (size_t)32 * 2048 * 64 * 2;  // (bh,64,S)
  bf16* attnb = (bf16*)ws; ws += (size_t)4096 * 1024 * 2;

  prep_kernel<<<8192, 256, 0, stream>>>(x, xb, w_qkv, wqkvt, w_o, wot);
  gemm_bt_kernel<0, 4><<<dim3(24, 32), 256, 0, stream>>>(
      xb, wqkvt, b_qkv, nullptr, qb, kb, vtb, 3072, 1024);
  attn_kernel<<<512, 256, 0, stream>>>(qb, kb, vtb, attnb);
  gemm_bt_kernel<1, 2><<<dim3(8, 64), 256, 0, stream>>>(
      attnb, wot, b_o, out, nullptr, nullptr, nullptr, 1024, 1024);
}

// Round 9
// 175.923 us; speedup vs baseline: 1.0881x; 1.0881x over previous
//
#include <hip/hip_runtime.h>
#include <stdint.h>

// ---------------------------------------------------------------------------
// MultiheadMaskedAttention (B=2, S=2048, H=1024, 16 heads x d=64)
// R9: attn with (1) 16-row waves, 512x512-thread blocks -> 4096 waves =
// 4/SIMD (2x latency hiding; 32-row waves cap at 2/SIMD structurally), and
// (2) S^T = K*Q^T operand swap so the C-frag holds 4 consecutive s per lane:
// P round-trip becomes 4 ds_write_b64 + 2 ds_read_b128 per iter (was 32
// b16 writes + 4 b128 reads, 1 conflict/write measured). P stored [q][s]
// stride 72 (write+read both at conflict-free minimum), read as PV A-frag.
// KV staging/swizzle/dbuf/pairing as R8. GEMMs/prep unchanged.
// ---------------------------------------------------------------------------

typedef __bf16 bf16;
typedef __attribute__((ext_vector_type(8))) __bf16 bf16x8;
typedef __attribute__((ext_vector_type(4))) __bf16 bf16x4;
typedef __attribute__((ext_vector_type(4))) float floatx4;

#define SCL 0.18033688011112042f  // (1/sqrt(64)) * log2(e)

__device__ __forceinline__ floatx4 mfma_bf16(bf16x8 a, bf16x8 b, floatx4 c) {
  // A: m=lane&15, k=quad*8+j ; B: n=lane&15, k=quad*8+j ; D: n=lane&15,
  // m=quad*4+reg  [verified m89/m91]
  return __builtin_amdgcn_mfma_f32_16x16x32_bf16(a, b, c, 0, 0, 0);
}

__device__ __forceinline__ void cp_g2l_16(const bf16* g, bf16* l) {
  // async global->LDS, 16B/lane; LDS dest = wave-uniform base + lane*16
  __builtin_amdgcn_global_load_lds(
      (const __attribute__((address_space(1))) void*)g,
      (__attribute__((address_space(3))) void*)l, 16, 0, 0);
}

// ---- merged prep: cast x -> bf16 ; cast+transpose w_qkv, w_o ----
__global__ __launch_bounds__(256) void prep_kernel(
    const float* __restrict__ x, bf16* __restrict__ xb,
    const float* __restrict__ w_qkv, bf16* __restrict__ wqkvt,
    const float* __restrict__ w_o, bf16* __restrict__ wot) {
  const int b = blockIdx.x;
  const int tid = threadIdx.x;
  if (b < 4096) {
    const int i = (b * 256 + tid) * 4;
    floatx4 v = *(const floatx4*)(x + i);
    bf16x4 o;
    o[0] = (bf16)v[0]; o[1] = (bf16)v[1]; o[2] = (bf16)v[2]; o[3] = (bf16)v[3];
    *(bf16x4*)(xb + i) = o;
    return;
  }
  __shared__ float tile[32][33];
  const float* W; bf16* Wt; int K, N, n0, k0;
  if (b < 7168) {
    const int bb = b - 4096;
    W = w_qkv; Wt = wqkvt; K = 1024; N = 3072;
    n0 = (bb % 96) * 32; k0 = (bb / 96) * 32;
  } else {
    const int bb = b - 7168;
    W = w_o; Wt = wot; K = 1024; N = 1024;
    n0 = (bb & 31) * 32; k0 = (bb >> 5) * 32;
  }
  const int tx = tid & 31, ty = tid >> 5;
  for (int i = 0; i < 4; ++i)
    tile[ty + 8 * i][tx] = W[(size_t)(k0 + ty + 8 * i) * N + n0 + tx];
  __syncthreads();
  for (int i = 0; i < 4; ++i)
    Wt[(size_t)(n0 + ty + 8 * i) * K + k0 + tx] = (bf16)tile[tx][ty + 8 * i];
}

// ---- GEMM: C = A(M x K bf16 rm) * Bt(N x K bf16 rm)^T + bias ----
template <int MODE, int MI>
__global__ __launch_bounds__(256, 3) void gemm_bt_kernel(
    const bf16* __restrict__ A, const bf16* __restrict__ Bt,
    const float* __restrict__ bias, float* __restrict__ outF,
    bf16* __restrict__ qb, bf16* __restrict__ kb, bf16* __restrict__ vtb,
    int N, int K) {
  constexpr int BM = MI * 32;
  __shared__ bf16 As[BM * 32];
  __shared__ bf16 Bs[128 * 32];
  const int tid = threadIdx.x;
  const int w = tid >> 6, lane = tid & 63;
  const int l16 = lane & 15, quad = lane >> 4;
  const int m0 = blockIdx.y * BM, n0 = blockIdx.x * 128;
  const int wm = (w & 1) * (BM / 2), wn = (w >> 1) * 64;

  const int arow = w * (BM / 4) + (lane >> 2);
  const int acol = (lane & 3) * 8;
  const bf16* Ag = A + (size_t)(m0 + arow) * K + acol;
  bf16* Al = As + arow * 32 + acol;
  const int brow = w * 32 + (lane >> 2);
  const bf16* Bg = Bt + (size_t)(n0 + brow) * K + acol;
  bf16* Bl = Bs + brow * 32 + acol;

  floatx4 acc[MI][4];
#pragma unroll
  for (int i = 0; i < MI; ++i)
#pragma unroll
    for (int j = 0; j < 4; ++j) acc[i][j] = (floatx4){0.f, 0.f, 0.f, 0.f};

  for (int k0 = 0; k0 < K; k0 += 32) {
    __syncthreads();
    cp_g2l_16(Ag + k0, Al);
    if (MI == 4) cp_g2l_16(Ag + (size_t)16 * K + k0, Al + 16 * 32);
    cp_g2l_16(Bg + k0, Bl);
    cp_g2l_16(Bg + (size_t)16 * K + k0, Bl + 16 * 32);
    __syncthreads();
    bf16x8 af[MI], bfr[4];
#pragma unroll
    for (int i = 0; i < MI; ++i)
      af[i] = *(const bf16x8*)(&As[(wm + i * 16 + l16) * 32 + quad * 8]);
#pragma unroll
    for (int j = 0; j < 4; ++j)
      bfr[j] = *(const bf16x8*)(&Bs[(wn + j * 16 + l16) * 32 + quad * 8]);
#pragma unroll
    for (int i = 0; i < MI; ++i)
#pragma unroll
      for (int j = 0; j < 4; ++j)
        acc[i][j] = mfma_bf16(af[i], bfr[j], acc[i][j]);
  }

#pragma unroll
  for (int i = 0; i < MI; ++i)
#pragma unroll
    for (int j = 0; j < 4; ++j) {
      const int nn = n0 + wn + j * 16 + l16;
      const float bv = bias[nn];
      const int mbase = m0 + wm + i * 16 + quad * 4;
      if (MODE == 1) {
#pragma unroll
        for (int r = 0; r < 4; ++r)
          outF[(size_t)(mbase + r) * N + nn] = acc[i][j][r] + bv;
      } else {
        const int which = nn >> 10;  // uniform per block
        const int rem = nn & 1023;
        const int h = rem >> 6, d = rem & 63;
        const int b = mbase >> 11, s = mbase & 2047;
        const size_t bh = (size_t)(b * 16 + h);
        if (which == 2) {
          bf16x4 pk;
#pragma unroll
          for (int r = 0; r < 4; ++r) pk[r] = (bf16)(acc[i][j][r] + bv);
          *(bf16x4*)(vtb + (bh * 64 + d) * 2048 + s) = pk;
        } else if (which == 0) {
#pragma unroll
          for (int r = 0; r < 4; ++r)
            qb[(bh * 2048 + s + r) * 64 + d] = (bf16)((acc[i][j][r] + bv) * SCL);
        } else {
#pragma unroll
          for (int r = 0; r < 4; ++r)
            kb[(bh * 2048 + s + r) * 64 + d] = (bf16)(acc[i][j][r] + bv);
        }
      }
    }
}

// ---- Flash attention, causal: 16-row waves, S^T swap, b64 P round-trip. --
// 512 blocks x 512 threads. Waves 0-3 = 16-row subtiles of 64-row group p,
// waves 4-7 = group 31-p. All 8 waves share the staged dbuf KV tile.
// S^T = K*Q^T: C-frag lane(quad,l16) holds q=l16, s=nk*16+quad*4+r ->
// pack 4 consecutive s as one b64 into P[q][s] (stride 72); PV reads P as
// A-frag (m=q=l16, k=s=quad*8+j) with 2 b128 reads. O C-frag: q=quad*4+r,
// d=nd*16+l16. l via ones-B MFMA on the P A-frags.
__global__ __launch_bounds__(512, 4) void attn_kernel(
    const bf16* __restrict__ Qb, const bf16* __restrict__ Kb,
    const bf16* __restrict__ Vtb, bf16* __restrict__ attnb) {
  __shared__ bf16 Ks[2][4096];   // [buf][64 s-rows x 64 d] swizzled chunks
  __shared__ bf16 Vs[2][4096];   // [buf][64 d-rows x 64 s] swizzled chunks
  __shared__ bf16 Ps[8 * 1152];  // per-wave P: 16 q-rows x 72 (s-major)
  const int bid = blockIdx.x;
  const int bh = (bid & 7) * 4 + ((bid >> 3) & 3);  // 4 heads per XCD
  const int p = bid >> 5;                           // pair id 0..15 (big first)
  const int tid = threadIdx.x;
  const int w = tid >> 6, lane = tid & 63;
  const int l16 = lane & 15, quad = lane >> 4;
  const int g = (w < 4) ? p : (31 - p);  // this wave's 64-row group
  const int q0 = g * 64 + (w & 3) * 16;  // this wave's 16 q-rows
  const int b = bh >> 4, h = bh & 15;
  const bf16* Qh = Qb + (size_t)bh * 2048 * 64;
  const bf16* Kh = Kb + (size_t)bh * 2048 * 64;
  const bf16* Vh = Vtb + (size_t)bh * 64 * 2048;
  bf16* Pw = Ps + w * 1152;

  const int nt = 32 - p;   // staging iterations (max of the two ranges)
  const int wdiag = g;     // this wave's diagonal KV tile

  // staging: thread tid copies 16B chunk tid of K and of V (512 chunks/tile)
  // dest chunk c: row=c>>3, slot=c&7 holds source chunk (slot-row)&7
  const int srow = tid >> 3;
  const int ssl = ((tid & 7) - srow) & 7;
  const int ksrc = srow * 64 + ssl * 8;
  const int vsrc = srow * 2048 + ssl * 8;

  // Q B-frags held in registers all kernel
  bf16x8 qf[2];
#pragma unroll
  for (int kq = 0; kq < 2; ++kq)
    qf[kq] = *(const bf16x8*)(Qh + (size_t)(q0 + l16) * 64 + kq * 32 + quad * 8);
  bf16x8 ones;
#pragma unroll
  for (int j = 0; j < 8; ++j) ones[j] = (bf16)1.0f;

  floatx4 O[4], Ol;
#pragma unroll
  for (int nd = 0; nd < 4; ++nd) O[nd] = (floatx4){0.f, 0.f, 0.f, 0.f};
  Ol = (floatx4){0.f, 0.f, 0.f, 0.f};

  // prologue: stage tile 0 into buffer 0
  cp_g2l_16(Kh + ksrc, &Ks[0][tid * 8]);
  cp_g2l_16(Vh + vsrc, &Vs[0][tid * 8]);

  int cur = 0;
  for (int t = 0; t < nt; ++t, cur ^= 1) {
    __syncthreads();  // buf[cur] staged; all waves done with buf[cur^1]
    if (t + 1 < nt) {  // prefetch t+1 into the other buffer
      const int nb = cur ^ 1;
      cp_g2l_16(Kh + (size_t)(t + 1) * 4096 + ksrc, &Ks[nb][tid * 8]);
      cp_g2l_16(Vh + (t + 1) * 64 + vsrc, &Vs[nb][tid * 8]);
    }

    if (t > wdiag) continue;  // fully-masked tile for this wave
    const bool diag = (t == wdiag);
    const bf16* KsC = Ks[cur];
    const bf16* VsC = Vs[cur];

    // K A-frags: A[m=s=nk*16+l16][k=d=kq*32+quad*8+j] (swizzled slots)
    bf16x8 kf[4][2];
#pragma unroll
    for (int nk = 0; nk < 4; ++nk)
#pragma unroll
      for (int kq = 0; kq < 2; ++kq) {
        const int row = nk * 16 + l16;
        kf[nk][kq] = *(const bf16x8*)(
            &KsC[row * 64 + ((kq * 4 + quad + row) & 7) * 8]);
      }

    // S^T = K * Q^T : D[s][q], lane holds q=l16, s=nk*16+quad*4+r
    floatx4 sf[4];
#pragma unroll
    for (int nk = 0; nk < 4; ++nk) {
      floatx4 a = (floatx4){0.f, 0.f, 0.f, 0.f};
      a = mfma_bf16(kf[nk][0], qf[0], a);
      a = mfma_bf16(kf[nk][1], qf[1], a);
      sf[nk] = a;
    }

    // V B-frags issued early (independent of softmax)
    bf16x8 vf[4][2];
#pragma unroll
    for (int nd = 0; nd < 4; ++nd)
#pragma unroll
      for (int kq = 0; kq < 2; ++kq) {
        const int row = nd * 16 + l16;
        vf[nd][kq] = *(const bf16x8*)(
            &VsC[row * 64 + ((kq * 4 + quad + row) & 7) * 8]);
      }

    // mask -> exp2 -> pack 4 consecutive s -> one b64 write per nk
#pragma unroll
    for (int nk = 0; nk < 4; ++nk) {
      bf16x4 pk;
#pragma unroll
      for (int r = 0; r < 4; ++r) {
        float s = sf[nk][r];
        if (diag) {
          const int kc = t * 64 + nk * 16 + quad * 4 + r;
          const int qrow = q0 + l16;
          s = (kc <= qrow) ? s : -1e30f;
        }
        pk[r] = (bf16)__builtin_amdgcn_exp2f(s);
      }
      *(bf16x4*)(&Pw[l16 * 72 + nk * 16 + quad * 4]) = pk;
    }

    // P A-frags: A[m=q=l16][k=s=kq*32+quad*8+j] (b128; compiler inserts lgkm)
    bf16x8 pf[2];
    pf[0] = *(const bf16x8*)(&Pw[l16 * 72 + quad * 8]);
    pf[1] = *(const bf16x8*)(&Pw[l16 * 72 + 32 + quad * 8]);

    // O[q][d] += P V ; l[q] += P * 1
#pragma unroll
    for (int nd = 0; nd < 4; ++nd) {
      floatx4 o = O[nd];
      o = mfma_bf16(pf[0], vf[nd][0], o);
      o = mfma_bf16(pf[1], vf[nd][1], o);
      O[nd] = o;
    }
    Ol = mfma_bf16(pf[0], ones, Ol);
    Ol = mfma_bf16(pf[1], ones, Ol);
  }

  // epilogue: O C-frag lane holds q=q0+quad*4+r, d=nd*16+l16
#pragma unroll
  for (int r = 0; r < 4; ++r) {
    const int qrow = q0 + quad * 4 + r;
    const float inv = 1.f / Ol[r];
#pragma unroll
    for (int nd = 0; nd < 4; ++nd)
      attnb[((size_t)(b * 2048 + qrow)) * 1024 + h * 64 + nd * 16 + l16] =
          (bf16)(O[nd][r] * inv);
  }
}

// ---------------------------------------------------------------------------
extern "C" void kernel_launch(void* const* d_in, const int* in_sizes, int n_in,
                              void* d_out, int out_size, void* d_ws, size_t ws_size,
                              hipStream_t stream) {
  const float* x     = (const float*)d_in[0];  // (2,2048,1024)
  const float* w_qkv = (const float*)d_in[1];  // (1024,3072)
  const float* b_qkv = (const float*)d_in[2];  // (3072)
  const float* w_o   = (const float*)d_in[3];  // (1024,1024)
  const float* b_o   = (const float*)d_in[4];  // (1024)
  float* out = (float*)d_out;                  // (2,2048,1024) fp32

  char* ws = (char*)d_ws;
  bf16* xb    = (bf16*)ws; ws += (size_t)4096 * 1024 * 2;
  bf16* wqkvt = (bf16*)ws; ws += (size_t)3072 * 1024 * 2;
  bf16* wot   = (bf16*)ws; ws += (size_t)1024 * 1024 * 2;
  bf16* qb    = (bf16*)ws; ws += (size_t)32 * 2048 * 64 * 2;
  bf16* kb    = (bf16*)ws; ws += (size_t)32 * 2048 * 64 * 2;
  bf16* vtb   = (bf16*)ws; ws += (size_t)32 * 2048 * 64 * 2;  // (bh,64,S)
  bf16* attnb = (bf16*)ws; ws += (size_t)4096 * 1024 * 2;

  prep_kernel<<<8192, 256, 0, stream>>>(x, xb, w_qkv, wqkvt, w_o, wot);
  gemm_bt_kernel<0, 4><<<dim3(24, 32), 256, 0, stream>>>(
      xb, wqkvt, b_qkv, nullptr, qb, kb, vtb, 3072, 1024);
  attn_kernel<<<512, 512, 0, stream>>>(qb, kb, vtb, attnb);
  gemm_bt_kernel<1, 2><<<dim3(8, 64), 256, 0, stream>>>(
      attnb, wot, b_o, out, nullptr, nullptr, nullptr, 1024, 1024);
}